// Round 6
// baseline (2881.222 us; speedup 1.0000x reference)
//
#include <hip/hip_runtime.h>

#define L_T 512
#define BATCH 1024
#define LB (L_T*BATCH)
#define NT (LB/64)

typedef short bf16x8 __attribute__((ext_vector_type(8)));
typedef float f32x4 __attribute__((ext_vector_type(4)));
typedef unsigned short u16;

#define MFMA_B16(a,b,c) __builtin_amdgcn_mfma_f32_16x16x32_bf16((a),(b),(c),0,0,0)

union U8 { unsigned u[4]; uint4 q; bf16x8 v; };

__device__ __forceinline__ short f2bs(float f){
  union{float f; unsigned u;} c; c.f=f;
  unsigned r = (c.u + 0x7FFFu + ((c.u>>16)&1u)) >> 16;
  return (short)r;
}

__device__ __forceinline__ unsigned cvtpk(float lo, float hi){
  unsigned d;
  asm("v_cvt_pk_bf16_f32 %0, %1, %2" : "=v"(d) : "v"(lo), "v"(hi));
  return d;
}

__device__ __forceinline__ f32x4 unpk(uint2 g){
  f32x4 r;
  r[0] = __uint_as_float(g.x << 16);
  r[1] = __uint_as_float(g.x & 0xffff0000u);
  r[2] = __uint_as_float(g.y << 16);
  r[3] = __uint_as_float(g.y & 0xffff0000u);
  return r;
}

__device__ __forceinline__ float sigmoidf_(float x){ return 1.0f/(1.0f + __expf(-x)); }
__device__ __forceinline__ float tanhf_(float x){ return 1.0f - 2.0f/(1.0f + __expf(2.0f*x)); }

__device__ __forceinline__ void store8(u16* d, float4 a, float4 b){
  bf16x8 v;
  v[0]=f2bs(a.x); v[1]=f2bs(a.y); v[2]=f2bs(a.z); v[3]=f2bs(a.w);
  v[4]=f2bs(b.x); v[5]=f2bs(b.y); v[6]=f2bs(b.z); v[7]=f2bs(b.w);
  *(bf16x8*)d = v;
}

__device__ __forceinline__ bf16x8 bfrag_f32(const float* p){
  float4 a = *(const float4*)p;
  float4 b = *(const float4*)(p+4);
  bf16x8 v;
  v[0]=f2bs(a.x); v[1]=f2bs(a.y); v[2]=f2bs(a.z); v[3]=f2bs(a.w);
  v[4]=f2bs(b.x); v[5]=f2bs(b.y); v[6]=f2bs(b.z); v[7]=f2bs(b.w);
  return v;
}

// hidden/gate-row permutation: slot (m, r) -> index H
__device__ __forceinline__ int Hmap(int m, int r){
  return ((r>>2)*8) + (r&3) + ((m&1)*4) + ((m>>1)*32);
}

// ---------------------------------------------------------------------------
// GI GEMM helper: D(slots) = W_perm · act^T (+bias C-init), store bf16 in
// tile-slot order. act staged in LDS [64][72] bf16 (rows = block's 64 batch
// rows); each wave handles its own 16 rows (n = l15).
//   W: [192][wstride] f32, cols wcoloff..wcoloff+63 used (KC=2).
//   bi/bh: bias ptrs (bh added for g<2 only; pass nullptr to skip bias and
//   use partial-C from gi buffers instead).
// gi0: tiles 0..7 (stride0 u16/row), gi1: tiles 8..11 (stride1) or
// gi1==nullptr -> all 12 tiles in gi0.
// ---------------------------------------------------------------------------
__device__ __forceinline__ void gi_gemm(
    const u16* xe, int rs, int l15, int l4, size_t row0,
    const float* __restrict__ W, int wstride, int wcoloff,
    const float* __restrict__ bi, const float* __restrict__ bh,
    u16* __restrict__ gi0, int stride0, u16* __restrict__ gi1, int stride1)
{
  // B-frags: act[batch l15][k]
  U8 xb0, xb1;
  xb0.v = *(const bf16x8*)(xe + (rs + l15)*72 + l4*8);
  xb1.v = *(const bf16x8*)(xe + (rs + l15)*72 + 32 + l4*8);

  const size_t grow = row0 + rs + l15;   // this lane's batch row (as n=l15 within wave)

  #pragma unroll
  for (int g = 0; g < 3; ++g) {
    #pragma unroll
    for (int m = 0; m < 4; ++m) {
      int tg = g*4 + m;
      // A-frags: W rows permuted (row l15 of tile -> W row g*64+H(m,l15))
      int wr = g*64 + Hmap(m, l15);
      bf16x8 a0 = bfrag_f32(W + (size_t)wr*wstride + wcoloff + l4*8);
      bf16x8 a1 = bfrag_f32(W + (size_t)wr*wstride + wcoloff + 32 + l4*8);
      // C-init
      f32x4 cin;
      if (bi) {
        int bidx = g*64 + ((m>>1)*32) + ((m&1)*4) + 8*l4;
        float4 c1 = *(const float4*)(bi + bidx);
        cin[0]=c1.x; cin[1]=c1.y; cin[2]=c1.z; cin[3]=c1.w;
        if (g < 2 && bh) {
          float4 c2 = *(const float4*)(bh + bidx);
          cin[0]+=c2.x; cin[1]+=c2.y; cin[2]+=c2.z; cin[3]+=c2.w;
        }
      } else {
        // partial C from gi buffers
        const u16* src = (tg < 8 || !gi1) ? (gi0 + grow*(size_t)stride0 + tg*16 + 4*l4)
                                          : (gi1 + grow*(size_t)stride1 + (tg-8)*16 + 4*l4);
        uint2 p = *(const uint2*)src;
        cin = unpk(p);
      }
      f32x4 acc = MFMA_B16(a0, xb0.v, cin);
      acc       = MFMA_B16(a1, xb1.v, acc);
      // pack + store
      uint2 o; o.x = cvtpk(acc[0], acc[1]); o.y = cvtpk(acc[2], acc[3]);
      u16* dst = (tg < 8 || !gi1) ? (gi0 + grow*(size_t)stride0 + tg*16 + 4*l4)
                                  : (gi1 + grow*(size_t)stride1 + (tg-8)*16 + 4*l4);
      *(uint2*)dst = o;
    }
  }
}

// ---------------------------------------------------------------------------
// K1: preprocess (2 layers) + fused GI GEMM.
//   x-branch: x_emb -> f32 output; GI_inf = iWih_perm · x_emb + (ibih+ibhh / ibih)
//   u-branch: u_emb; GI_gen_partial = gWih[:,64:128]_perm · u_emb + gen biases
// ---------------------------------------------------------------------------
__device__ __forceinline__ void pre_body(
    int bid,
    const float* __restrict__ src, const float* __restrict__ W1,
    const float* __restrict__ b1, const float* __restrict__ W2,
    const float* __restrict__ b2,
    float* __restrict__ out_f32,
    const float* __restrict__ GW, int wstride, int wcoloff,
    const float* __restrict__ gbi, const float* __restrict__ gbh,
    u16* __restrict__ gi0, int stride0, u16* __restrict__ gi1, int stride1)
{
  __shared__ u16 in_t[64*40];
  __shared__ u16 w1t[64*40];
  __shared__ u16 w2t[64*88];
  __shared__ u16 t1t[64*88];
  __shared__ u16 xe[64*72];
  __shared__ float lb1[64], lb2[64];

  const int t = threadIdx.x;
  const size_t row0 = (size_t)bid * 64;

  {
    int r = t>>2, q = t&3;
    const float* ps = src + (row0 + r)*32 + q*8;
    store8(in_t + r*40 + q*8, *(const float4*)ps, *(const float4*)(ps+4));
    const float* pw = W1 + r*32 + q*8;
    store8(w1t + r*40 + q*8, *(const float4*)pw, *(const float4*)(pw+4));
    const float* pw2 = W2 + r*64 + q*16;
    store8(w2t + r*88 + q*16,     *(const float4*)pw2,     *(const float4*)(pw2+4));
    store8(w2t + r*88 + q*16 + 8, *(const float4*)(pw2+8), *(const float4*)(pw2+12));
    if (t < 64) lb1[t] = b1[t];
    else if (t < 128) lb2[t-64] = b2[t-64];
  }
  __syncthreads();

  const int lane = t & 63, wave = t >> 6;
  const int l15 = lane & 15, l4 = lane >> 4;
  const int rs = wave*16;

  // layer 1 (K=32)
  {
    bf16x8 a = *(const bf16x8*)(in_t + (rs + l15)*40 + l4*8);
    #pragma unroll
    for (int ct = 0; ct < 4; ++ct) {
      f32x4 acc = {0.f,0.f,0.f,0.f};
      bf16x8 bw = *(const bf16x8*)(w1t + (ct*16 + l15)*40 + l4*8);
      acc = MFMA_B16(a, bw, acc);
      float bias = lb1[ct*16 + l15];
      #pragma unroll
      for (int i = 0; i < 4; ++i) {
        float v = fmaxf(acc[i] + bias, 0.f);
        t1t[(rs + l4*4 + i)*88 + ct*16 + l15] = (u16)f2bs(v);
      }
    }
  }
  __syncthreads();

  // layer 2 (K=64): emit f32 (optional) + restage bf16 into xe
  {
    bf16x8 a0 = *(const bf16x8*)(t1t + (rs + l15)*88 + l4*8);
    bf16x8 a1 = *(const bf16x8*)(t1t + (rs + l15)*88 + 32 + l4*8);
    #pragma unroll
    for (int ct = 0; ct < 4; ++ct) {
      f32x4 acc = {0.f,0.f,0.f,0.f};
      bf16x8 b0 = *(const bf16x8*)(w2t + (ct*16 + l15)*88 + l4*8);
      bf16x8 b1v = *(const bf16x8*)(w2t + (ct*16 + l15)*88 + 32 + l4*8);
      acc = MFMA_B16(a0, b0, acc);
      acc = MFMA_B16(a1, b1v, acc);
      float bias = lb2[ct*16 + l15];
      #pragma unroll
      for (int i = 0; i < 4; ++i) {
        float v = fmaxf(acc[i] + bias, 0.f);
        size_t gr = row0 + rs + l4*4 + i;
        int col = ct*16 + l15;
        if (out_f32) out_f32[gr*64 + col] = v;
        xe[(rs + l4*4 + i)*72 + col] = (u16)f2bs(v);
      }
    }
  }
  __syncthreads();

  gi_gemm(xe, rs, l15, l4, row0, GW, wstride, wcoloff, gbi, gbh,
          gi0, stride0, gi1, stride1);
}

__global__ __launch_bounds__(256) void k_pre2(
    const float* __restrict__ obs,
    const float* __restrict__ pxW1, const float* __restrict__ pxb1,
    const float* __restrict__ pxW2, const float* __restrict__ pxb2,
    float* __restrict__ xembf32,
    const float* __restrict__ iWih,
    const float* __restrict__ ibih, const float* __restrict__ ibhh,
    u16* __restrict__ gi_inf,
    const float* __restrict__ ext,
    const float* __restrict__ puW1, const float* __restrict__ pub1,
    const float* __restrict__ puW2, const float* __restrict__ pub2,
    const float* __restrict__ gWih,
    const float* __restrict__ gbih, const float* __restrict__ gbhh,
    u16* __restrict__ gia, u16* __restrict__ gib)
{
  int bid = blockIdx.x;
  if (bid < NT)
    pre_body(bid, obs, pxW1, pxb1, pxW2, pxb2, xembf32,
             iWih, 64, 0, ibih, ibhh, gi_inf, 192, nullptr, 0);
  else
    pre_body(bid - NT, ext, puW1, pub1, puW2, pub2, nullptr,
             gWih, 128, 64, gbih, gbhh, gia, 128, gib, 64);
}

// ---------------------------------------------------------------------------
// K2: posterior DBlock + sample + z_emb + GI_gen finalize (adds z-part).
// ---------------------------------------------------------------------------
__global__ __launch_bounds__(256) void k_posterior_z(
    const u16* __restrict__ dseq,             // [LB][64] bf16
    const float* __restrict__ eps,            // [LB][32]
    const float* __restrict__ W1, const float* __restrict__ b1,
    const float* __restrict__ W2, const float* __restrict__ b2,
    const float* __restrict__ Wmu, const float* __restrict__ bmu,
    const float* __restrict__ Wls, const float* __restrict__ bls,
    const float* __restrict__ zW1, const float* __restrict__ zb1,
    const float* __restrict__ zW2, const float* __restrict__ zb2,
    const float* __restrict__ gWih,
    float* __restrict__ out_mu, float* __restrict__ out_ls, float* __restrict__ out_s,
    u16* __restrict__ gia, u16* __restrict__ gib)
{
  __shared__ u16 dt[64*88], w1t[64*88], w2t[64*88], tt[64*88], zw2t[64*88];
  __shared__ u16 zw1t[64*40], st[64*40];
  __shared__ u16 wmut[32*88], wlst[32*88];
  __shared__ float lb1[64], lb2[64], lbz1[64], lbz2[64], lbmu[32], lbls[32];

  const int t = threadIdx.x;
  const size_t row0 = (size_t)blockIdx.x * 64;

  {
    int r = t>>2, q = t&3;
    const u16* pd = dseq + (row0 + r)*64 + q*16;
    *(bf16x8*)(dt + r*88 + q*16)     = *(const bf16x8*)pd;
    *(bf16x8*)(dt + r*88 + q*16 + 8) = *(const bf16x8*)(pd + 8);
    const float* p1 = W1 + r*64 + q*16;
    store8(w1t + r*88 + q*16,     *(const float4*)p1,     *(const float4*)(p1+4));
    store8(w1t + r*88 + q*16 + 8, *(const float4*)(p1+8), *(const float4*)(p1+12));
    const float* p2 = W2 + r*64 + q*16;
    store8(w2t + r*88 + q*16,     *(const float4*)p2,     *(const float4*)(p2+4));
    store8(w2t + r*88 + q*16 + 8, *(const float4*)(p2+8), *(const float4*)(p2+12));
    const float* pz2 = zW2 + r*64 + q*16;
    store8(zw2t + r*88 + q*16,     *(const float4*)pz2,     *(const float4*)(pz2+4));
    store8(zw2t + r*88 + q*16 + 8, *(const float4*)(pz2+8), *(const float4*)(pz2+12));
    const float* pz1 = zW1 + r*32 + q*8;
    store8(zw1t + r*40 + q*8, *(const float4*)pz1, *(const float4*)(pz1+4));
    if (t < 128) {
      int r2 = t>>2, q2 = t&3;
      const float* pm = Wmu + r2*64 + q2*16;
      store8(wmut + r2*88 + q2*16,     *(const float4*)pm,     *(const float4*)(pm+4));
      store8(wmut + r2*88 + q2*16 + 8, *(const float4*)(pm+8), *(const float4*)(pm+12));
    } else {
      int t2 = t - 128; int r2 = t2>>2, q2 = t2&3;
      const float* pl = Wls + r2*64 + q2*16;
      store8(wlst + r2*88 + q2*16,     *(const float4*)pl,     *(const float4*)(pl+4));
      store8(wlst + r2*88 + q2*16 + 8, *(const float4*)(pl+8), *(const float4*)(pl+12));
    }
    if (t < 64) { lb1[t] = b1[t]; lbz1[t] = zb1[t]; }
    else if (t < 128) { lb2[t-64] = b2[t-64]; lbz2[t-64] = zb2[t-64]; }
    else if (t < 160) lbmu[t-128] = bmu[t-128];
    else if (t < 192) lbls[t-160] = bls[t-160];
  }
  __syncthreads();

  const int lane = t & 63, wave = t >> 6;
  const int l15 = lane & 15, l4 = lane >> 4;
  const int rs = wave*16;

  // gated hidden
  {
    bf16x8 a0 = *(const bf16x8*)(dt + (rs + l15)*88 + l4*8);
    bf16x8 a1 = *(const bf16x8*)(dt + (rs + l15)*88 + 32 + l4*8);
    #pragma unroll
    for (int ct = 0; ct < 4; ++ct) {
      f32x4 c1 = {0.f,0.f,0.f,0.f}, c2 = {0.f,0.f,0.f,0.f};
      bf16x8 w1a = *(const bf16x8*)(w1t + (ct*16 + l15)*88 + l4*8);
      bf16x8 w1b = *(const bf16x8*)(w1t + (ct*16 + l15)*88 + 32 + l4*8);
      bf16x8 w2a = *(const bf16x8*)(w2t + (ct*16 + l15)*88 + l4*8);
      bf16x8 w2b = *(const bf16x8*)(w2t + (ct*16 + l15)*88 + 32 + l4*8);
      c1 = MFMA_B16(a0, w1a, c1); c1 = MFMA_B16(a1, w1b, c1);
      c2 = MFMA_B16(a0, w2a, c2); c2 = MFMA_B16(a1, w2b, c2);
      float bb1 = lb1[ct*16 + l15], bb2 = lb2[ct*16 + l15];
      #pragma unroll
      for (int i = 0; i < 4; ++i) {
        float tv = fmaxf(c1[i] + bb1, 0.f) * sigmoidf_(c2[i] + bb2);
        tt[(rs + l4*4 + i)*88 + ct*16 + l15] = (u16)f2bs(tv);
      }
    }
  }
  __syncthreads();

  // heads + sample; park s (bf16) in st
  {
    bf16x8 a0 = *(const bf16x8*)(tt + (rs + l15)*88 + l4*8);
    bf16x8 a1 = *(const bf16x8*)(tt + (rs + l15)*88 + 32 + l4*8);
    #pragma unroll
    for (int ct = 0; ct < 2; ++ct) {
      f32x4 cmu = {0.f,0.f,0.f,0.f}, cls = {0.f,0.f,0.f,0.f};
      bf16x8 wma = *(const bf16x8*)(wmut + (ct*16 + l15)*88 + l4*8);
      bf16x8 wmb = *(const bf16x8*)(wmut + (ct*16 + l15)*88 + 32 + l4*8);
      bf16x8 wla = *(const bf16x8*)(wlst + (ct*16 + l15)*88 + l4*8);
      bf16x8 wlb = *(const bf16x8*)(wlst + (ct*16 + l15)*88 + 32 + l4*8);
      cmu = MFMA_B16(a0, wma, cmu); cmu = MFMA_B16(a1, wmb, cmu);
      cls = MFMA_B16(a0, wla, cls); cls = MFMA_B16(a1, wlb, cls);
      float bm = lbmu[ct*16 + l15], bl = lbls[ct*16 + l15];
      #pragma unroll
      for (int i = 0; i < 4; ++i) {
        size_t R = row0 + rs + l4*4 + i;
        int col = ct*16 + l15;
        float mu = cmu[i] + bm;
        float ls = cls[i] + bl;
        float e  = eps[R*32 + col];
        float s  = mu + __expf(0.5f*ls)*e;
        out_mu[R*32 + col] = mu;
        out_ls[R*32 + col] = ls;
        out_s [R*32 + col] = s;
        st[(rs + l4*4 + i)*40 + col] = (u16)f2bs(s);
      }
    }
  }
  __syncthreads();

  // z_emb layer 1 -> dt
  {
    bf16x8 a = *(const bf16x8*)(st + (rs + l15)*40 + l4*8);
    #pragma unroll
    for (int ct = 0; ct < 4; ++ct) {
      f32x4 acc = {0.f,0.f,0.f,0.f};
      bf16x8 bw = *(const bf16x8*)(zw1t + (ct*16 + l15)*40 + l4*8);
      acc = MFMA_B16(a, bw, acc);
      float bias = lbz1[ct*16 + l15];
      #pragma unroll
      for (int i = 0; i < 4; ++i) {
        float v = fmaxf(acc[i] + bias, 0.f);
        dt[(rs + l4*4 + i)*88 + ct*16 + l15] = (u16)f2bs(v);
      }
    }
  }
  __syncthreads();

  // z_emb layer 2 -> restage bf16 into w1t (dead)
  {
    bf16x8 a0 = *(const bf16x8*)(dt + (rs + l15)*88 + l4*8);
    bf16x8 a1 = *(const bf16x8*)(dt + (rs + l15)*88 + 32 + l4*8);
    #pragma unroll
    for (int ct = 0; ct < 4; ++ct) {
      f32x4 acc = {0.f,0.f,0.f,0.f};
      bf16x8 b0 = *(const bf16x8*)(zw2t + (ct*16 + l15)*88 + l4*8);
      bf16x8 b1v = *(const bf16x8*)(zw2t + (ct*16 + l15)*88 + 32 + l4*8);
      acc = MFMA_B16(a0, b0, acc);
      acc = MFMA_B16(a1, b1v, acc);
      float bias = lbz2[ct*16 + l15];
      #pragma unroll
      for (int i = 0; i < 4; ++i) {
        float v = fmaxf(acc[i] + bias, 0.f);
        w1t[(rs + l4*4 + i)*88 + ct*16 + l15] = (u16)f2bs(v);
      }
    }
  }
  __syncthreads();

  // GI_gen += gWih[:,0:64]_perm · z_emb  (C = partial from k_pre2-u)
  {
    // gi_gemm expects stride-72 LDS; w1t is stride 88 -> inline variant here
    U8 xb0, xb1;
    xb0.v = *(const bf16x8*)(w1t + (rs + l15)*88 + l4*8);
    xb1.v = *(const bf16x8*)(w1t + (rs + l15)*88 + 32 + l4*8);
    const size_t grow = row0 + rs + l15;
    #pragma unroll
    for (int g = 0; g < 3; ++g) {
      #pragma unroll
      for (int m = 0; m < 4; ++m) {
        int tg = g*4 + m;
        int wr = g*64 + Hmap(m, l15);
        bf16x8 a0 = bfrag_f32(gWih + (size_t)wr*128 + l4*8);
        bf16x8 a1 = bfrag_f32(gWih + (size_t)wr*128 + 32 + l4*8);
        u16* p = (tg < 8) ? (gia + grow*128 + tg*16 + 4*l4)
                          : (gib + grow*64 + (tg-8)*16 + 4*l4);
        uint2 part = *(const uint2*)p;
        f32x4 acc = unpk(part);
        acc = MFMA_B16(a0, xb0.v, acc);
        acc = MFMA_B16(a1, xb1.v, acc);
        uint2 o; o.x = cvtpk(acc[0], acc[1]); o.y = cvtpk(acc[2], acc[3]);
        *(uint2*)p = o;
      }
    }
  }
}

// ---------------------------------------------------------------------------
// K3/K4: GRU scan v6 — barrier-free, LDS-free.
// One wave per 16-batch group (64 blocks x 64 threads). Thread (l15,l4) owns
// h[batch l15][hidden {8l4..8l4+7} u {32+8l4..+7}] as 4 f32x4 (H-permuted
// tile slots). Packed bf16 of those values IS the next step's B-fragment.
// Per step: 12 MFMA-tile updates D = Whh_perm·h + gi (C-init), gate math,
// pack, store. GI prefetched 4-deep (static buffers via 4x-unrolled body).
// ---------------------------------------------------------------------------
template<bool IS_GEN>
__global__ __launch_bounds__(64, 1) void k_scan(
    const u16* __restrict__ gi0,   // inf: [LB][192]; gen: GIa [LB][128]
    const u16* __restrict__ gi1,   // gen: GIb [LB][64]; inf unused
    const float* __restrict__ Whh, // [192][64]
    const float* __restrict__ bhh, // [192]
    u16* __restrict__ outp,        // inf: dseq [LB][64]; gen: hpark ws rows [LB][128] (cols 0..63 used)
    float* __restrict__ hn)        // gen only
{
  const int t = threadIdx.x;
  const int l15 = t & 15, l4 = t >> 4;
  const int b0 = blockIdx.x * 16;

  constexpr int OSTR = IS_GEN ? 128 : 64;   // u16 row stride of outp

  // Whh A-frags (rows H-permuted)
  bf16x8 whhA[3][4][2];
  #pragma unroll
  for (int g = 0; g < 3; ++g)
    #pragma unroll
    for (int m = 0; m < 4; ++m) {
      int wr = g*64 + Hmap(m, l15);
      whhA[g][m][0] = bfrag_f32(Whh + (size_t)wr*64 + l4*8);
      whhA[g][m][1] = bfrag_f32(Whh + (size_t)wr*64 + 32 + l4*8);
    }
  // n-gate hidden bias (C-init), per tile m
  f32x4 bvh[4];
  #pragma unroll
  for (int m = 0; m < 4; ++m) {
    const float* p = bhh + 128 + ((m>>1)*32) + ((m&1)*4) + 8*l4;
    float4 b = *(const float4*)p;
    bvh[m][0]=b.x; bvh[m][1]=b.y; bvh[m][2]=b.z; bvh[m][3]=b.w;
  }

  // gi load bases (per-lane)
  const u16* gbase0 = gi0 + (size_t)(b0 + l15)*(IS_GEN ? 128 : 192) + 4*l4;
  const u16* gbase1 = IS_GEN ? (gi1 + (size_t)(b0 + l15)*64 + 4*l4) : nullptr;
  constexpr size_t GSTEP0 = (size_t)BATCH * (IS_GEN ? 128 : 192);
  constexpr size_t GSTEP1 = (size_t)BATCH * 64;

  // out base
  u16* obase = outp + (size_t)(b0 + l15)*OSTR + 8*l4;
  constexpr size_t OSTEP = (size_t)BATCH * OSTR;

  auto load_gi = [&](uint2 (&g)[12], int s){
    const u16* p0 = gbase0 + (size_t)s*GSTEP0;
    #pragma unroll
    for (int tg = 0; tg < (IS_GEN ? 8 : 12); ++tg)
      g[tg] = *(const uint2*)(p0 + tg*16);
    if (IS_GEN) {
      const u16* p1 = gbase1 + (size_t)s*GSTEP1;
      #pragma unroll
      for (int tg = 8; tg < 12; ++tg)
        g[tg] = *(const uint2*)(p1 + (tg-8)*16);
    }
  };

  f32x4 hp[4];
  #pragma unroll
  for (int m = 0; m < 4; ++m) hp[m] = (f32x4){0.f,0.f,0.f,0.f};
  U8 ha0, ha1;
  #pragma unroll
  for (int w = 0; w < 4; ++w) { ha0.u[w] = 0; ha1.u[w] = 0; }

  uint2 gA[12], gB[12], gC[12], gD[12];
  load_gi(gA, 0); load_gi(gB, 1); load_gi(gC, 2); load_gi(gD, 3);

  auto body = [&](uint2 (&g)[12], int s){
    // C-inits from gi (r/z) and n-gate gi addend
    f32x4 acc[3][4], gin[4];
    #pragma unroll
    for (int m = 0; m < 4; ++m) {
      acc[0][m] = unpk(g[m]);
      acc[1][m] = unpk(g[4+m]);
      acc[2][m] = bvh[m];
      gin[m]    = unpk(g[8+m]);
    }
    // prefetch for s+4 (registers free after unpack)
    int sn = (s + 4 < L_T) ? s + 4 : L_T - 1;
    load_gi(g, sn);

    // 24 MFMA
    #pragma unroll
    for (int m = 0; m < 4; ++m) {
      #pragma unroll
      for (int gg = 0; gg < 3; ++gg) {
        acc[gg][m] = MFMA_B16(whhA[gg][m][0], ha0.v, acc[gg][m]);
        acc[gg][m] = MFMA_B16(whhA[gg][m][1], ha1.v, acc[gg][m]);
      }
    }

    // gates + h update
    #pragma unroll
    for (int m = 0; m < 4; ++m) {
      #pragma unroll
      for (int i = 0; i < 4; ++i) {
        float r = sigmoidf_(acc[0][m][i]);
        float z = sigmoidf_(acc[1][m][i]);
        float n = tanhf_(gin[m][i] + r*acc[2][m][i]);
        hp[m][i] = z*(hp[m][i] - n) + n;
      }
    }

    // pack -> next B-frag AND output words
    ha0.u[0] = cvtpk(hp[0][0], hp[0][1]); ha0.u[1] = cvtpk(hp[0][2], hp[0][3]);
    ha0.u[2] = cvtpk(hp[1][0], hp[1][1]); ha0.u[3] = cvtpk(hp[1][2], hp[1][3]);
    ha1.u[0] = cvtpk(hp[2][0], hp[2][1]); ha1.u[1] = cvtpk(hp[2][2], hp[2][3]);
    ha1.u[2] = cvtpk(hp[3][0], hp[3][1]); ha1.u[3] = cvtpk(hp[3][2], hp[3][3]);

    // store h_s (inf: dseq row s; gen: park row s = dead GIa rows)
    u16* o = obase + (size_t)s*OSTEP;
    *(uint4*)o        = ha0.q;
    *(uint4*)(o + 32) = ha1.q;
  };

  for (int s = 0; s < L_T; s += 4) {
    body(gA, s);
    body(gB, s + 1);
    body(gC, s + 2);
    body(gD, s + 3);
  }

  if (IS_GEN) {
    float* hb = hn + (size_t)(b0 + l15)*64 + 8*l4;
    float4 v0; v0.x=hp[0][0]; v0.y=hp[0][1]; v0.z=hp[0][2]; v0.w=hp[0][3];
    float4 v1; v1.x=hp[1][0]; v1.y=hp[1][1]; v1.z=hp[1][2]; v1.w=hp[1][3];
    float4 v2; v2.x=hp[2][0]; v2.y=hp[2][1]; v2.z=hp[2][2]; v2.w=hp[2][3];
    float4 v3; v3.x=hp[3][0]; v3.y=hp[3][1]; v3.z=hp[3][2]; v3.w=hp[3][3];
    *(float4*)(hb)      = v0;
    *(float4*)(hb + 4)  = v1;
    *(float4*)(hb + 32) = v2;
    *(float4*)(hb + 36) = v3;
  }
}

// ---------------------------------------------------------------------------
// K5: expand parked bf16 h-seq (ws rows, shifted by one step) to f32 hseq.
// hseq[t] = park[t-1] for t>=1; hseq[0] = 0.
// ---------------------------------------------------------------------------
__global__ __launch_bounds__(256) void k_expand(
    const u16* __restrict__ park,   // [LB][128] u16 rows (cols 0..63 used)
    float* __restrict__ hseq)       // [LB][64]
{
  size_t e0 = ((size_t)blockIdx.x*256 + threadIdx.x)*8;
  size_t R = e0 >> 6;
  int col = (int)(e0 & 63);
  float4 v0, v1;
  if (R < BATCH) {
    v0.x=v0.y=v0.z=v0.w=0.f; v1 = v0;
  } else {
    U8 u; u.q = *(const uint4*)(park + (R - BATCH)*128 + col);
    v0.x = __uint_as_float((unsigned)(u.u[0]) << 16);
    v0.y = __uint_as_float(u.u[0] & 0xffff0000u);
    v0.z = __uint_as_float((unsigned)(u.u[1]) << 16);
    v0.w = __uint_as_float(u.u[1] & 0xffff0000u);
    v1.x = __uint_as_float((unsigned)(u.u[2]) << 16);
    v1.y = __uint_as_float(u.u[2] & 0xffff0000u);
    v1.z = __uint_as_float((unsigned)(u.u[3]) << 16);
    v1.w = __uint_as_float(u.u[3] & 0xffff0000u);
  }
  *(float4*)(hseq + R*64 + col)     = v0;
  *(float4*)(hseq + R*64 + col + 4) = v1;
}

// ---------------------------------------------------------------------------

extern "C" void kernel_launch(void* const* d_in, const int* in_sizes, int n_in,
                              void* d_out, int out_size, void* d_ws, size_t ws_size,
                              hipStream_t stream) {
  const float* ext  = (const float*)d_in[0];
  const float* obs  = (const float*)d_in[1];
  const float* eps  = (const float*)d_in[2];
  const float* puW1 = (const float*)d_in[3];  const float* pub1 = (const float*)d_in[4];
  const float* puW2 = (const float*)d_in[5];  const float* pub2 = (const float*)d_in[6];
  const float* pxW1 = (const float*)d_in[7];  const float* pxb1 = (const float*)d_in[8];
  const float* pxW2 = (const float*)d_in[9];  const float* pxb2 = (const float*)d_in[10];
  const float* pzW1 = (const float*)d_in[11]; const float* pzb1 = (const float*)d_in[12];
  const float* pzW2 = (const float*)d_in[13]; const float* pzb2 = (const float*)d_in[14];
  const float* poW1 = (const float*)d_in[15]; const float* pob1 = (const float*)d_in[16];
  const float* poW2 = (const float*)d_in[17]; const float* pob2 = (const float*)d_in[18];
  const float* poWmu= (const float*)d_in[19]; const float* pobmu= (const float*)d_in[20];
  const float* poWls= (const float*)d_in[21]; const float* pobls= (const float*)d_in[22];
  const float* iWih = (const float*)d_in[23]; const float* iWhh = (const float*)d_in[24];
  const float* ibih = (const float*)d_in[25]; const float* ibhh = (const float*)d_in[26];
  const float* gWih = (const float*)d_in[27]; const float* gWhh = (const float*)d_in[28];
  const float* gbih = (const float*)d_in[29]; const float* gbhh = (const float*)d_in[30];

  float* out = (float*)d_out;
  const size_t OFF_MU   = 0;
  const size_t OFF_LS   = (size_t)LB*32;
  const size_t OFF_S    = (size_t)LB*64;
  const size_t OFF_HSEQ = (size_t)LB*96;
  const size_t OFF_XEMB = (size_t)LB*96 + (size_t)LB*64;
  const size_t OFF_HN   = OFF_XEMB + (size_t)LB*64;

  u16* gi_inf = (u16*)(out + OFF_MU);                   // [LB][192] bf16 (parked in mu/ls/s)
  u16* gia    = (u16*)d_ws;                             // [LB][128] bf16 (GI_gen cols 0..127; later hpark)
  u16* gib    = (u16*)(out + OFF_HSEQ);                 // [LB][64]  bf16 (GI_gen cols 128..191)
  u16* dseq   = (u16*)(out + OFF_HSEQ) + (size_t)LB*64; // [LB][64]  bf16 (hseq 2nd half)

  // 1. x_emb (+GI_inf) and u_emb (+GI_gen partial)
  k_pre2<<<2*NT, 256, 0, stream>>>(obs, pxW1, pxb1, pxW2, pxb2, out + OFF_XEMB,
                                   iWih, ibih, ibhh, gi_inf,
                                   ext, puW1, pub1, puW2, pub2,
                                   gWih, gbih, gbhh, gia, gib);
  // 2. inference scan
  k_scan<false><<<64, 64, 0, stream>>>(gi_inf, nullptr, iWhh, ibhh, dseq, nullptr);
  // 3. posterior + sample + z_emb + GI_gen finalize (overwrites gi_inf region with mu/ls/s)
  k_posterior_z<<<NT, 256, 0, stream>>>(dseq, eps, poW1, pob1, poW2, pob2,
                                        poWmu, pobmu, poWls, pobls,
                                        pzW1, pzb1, pzW2, pzb2, gWih,
                                        out + OFF_MU, out + OFF_LS, out + OFF_S,
                                        gia, gib);
  // 4. generative scan (writes bf16 h into dead GIa rows + hn)
  k_scan<true><<<64, 64, 0, stream>>>(gia, gib, gWhh, gbhh, gia, out + OFF_HN);
  // 5. expand parked h to f32 hseq
  k_expand<<<(LB*64)/2048, 256, 0, stream>>>(gia, out + OFF_HSEQ);
}

// Round 7
// 1457.224 us; speedup vs baseline: 1.9772x; 1.9772x over previous
//
#include <hip/hip_runtime.h>

#define L_T 512
#define BATCH 1024
#define LB (L_T*BATCH)
#define NT (LB/64)

typedef short bf16x8 __attribute__((ext_vector_type(8)));
typedef float f32x4 __attribute__((ext_vector_type(4)));
typedef unsigned short u16;

#define MFMA_B16(a,b,c) __builtin_amdgcn_mfma_f32_16x16x32_bf16((a),(b),(c),0,0,0)

union U8 { unsigned u[4]; uint4 q; bf16x8 v; };

__device__ __forceinline__ short f2bs(float f){
  union{float f; unsigned u;} c; c.f=f;
  unsigned r = (c.u + 0x7FFFu + ((c.u>>16)&1u)) >> 16;
  return (short)r;
}

__device__ __forceinline__ unsigned cvtpk(float lo, float hi){
  unsigned d;
  asm("v_cvt_pk_bf16_f32 %0, %1, %2" : "=v"(d) : "v"(lo), "v"(hi));
  return d;
}

__device__ __forceinline__ f32x4 unpk(uint2 g){
  f32x4 r;
  r[0] = __uint_as_float(g.x << 16);
  r[1] = __uint_as_float(g.x & 0xffff0000u);
  r[2] = __uint_as_float(g.y << 16);
  r[3] = __uint_as_float(g.y & 0xffff0000u);
  return r;
}

// fast activations: rcp is v_rcp_f32 (~1ulp), exp via __expf (v_mul+v_exp)
__device__ __forceinline__ float fsig(float x){
  return __builtin_amdgcn_rcpf(1.0f + __expf(-x));
}
__device__ __forceinline__ float ftanh(float x){
  return 1.0f - 2.0f*__builtin_amdgcn_rcpf(1.0f + __expf(2.0f*x));
}

__device__ __forceinline__ void store8(u16* d, float4 a, float4 b){
  bf16x8 v;
  v[0]=f2bs(a.x); v[1]=f2bs(a.y); v[2]=f2bs(a.z); v[3]=f2bs(a.w);
  v[4]=f2bs(b.x); v[5]=f2bs(b.y); v[6]=f2bs(b.z); v[7]=f2bs(b.w);
  *(bf16x8*)d = v;
}

__device__ __forceinline__ bf16x8 bfrag_f32(const float* p){
  float4 a = *(const float4*)p;
  float4 b = *(const float4*)(p+4);
  bf16x8 v;
  v[0]=f2bs(a.x); v[1]=f2bs(a.y); v[2]=f2bs(a.z); v[3]=f2bs(a.w);
  v[4]=f2bs(b.x); v[5]=f2bs(b.y); v[6]=f2bs(b.z); v[7]=f2bs(b.w);
  return v;
}

// ---------------------------------------------------------------------------
// K1: preprocess (2 layers) + fused GI GEMM, PLAIN column layout.
// GI[row][g*64 + col] = Wih[g*64+col, :] . x_emb[row, :] + bias (r,z: bih+bhh;
// n: bih). Stores staged through LDS -> block-linear coalesced uint4 stores.
// ---------------------------------------------------------------------------
__device__ __forceinline__ void pre_body(
    int bid,
    const float* __restrict__ src, const float* __restrict__ W1,
    const float* __restrict__ b1, const float* __restrict__ W2,
    const float* __restrict__ b2,
    float* __restrict__ out_f32,
    const float* __restrict__ GW, int wstride, int wcoloff,
    const float* __restrict__ gbi, const float* __restrict__ gbh,
    u16* __restrict__ gi0, u16* __restrict__ gi1)  // inf: gi0=[LB][192],gi1=0; gen: gia[LB][128], gib[LB][64]
{
  __shared__ u16 in_t[64*40];
  __shared__ u16 w1t[64*40];
  __shared__ u16 w2t[64*88];
  __shared__ u16 t1t[64*88];
  __shared__ u16 xe[64*72];
  __shared__ u16 gst[64*200];
  __shared__ float lb1[64], lb2[64];

  const int t = threadIdx.x;
  const size_t row0 = (size_t)bid * 64;

  {
    int r = t>>2, q = t&3;
    const float* ps = src + (row0 + r)*32 + q*8;
    store8(in_t + r*40 + q*8, *(const float4*)ps, *(const float4*)(ps+4));
    const float* pw = W1 + r*32 + q*8;
    store8(w1t + r*40 + q*8, *(const float4*)pw, *(const float4*)(pw+4));
    const float* pw2 = W2 + r*64 + q*16;
    store8(w2t + r*88 + q*16,     *(const float4*)pw2,     *(const float4*)(pw2+4));
    store8(w2t + r*88 + q*16 + 8, *(const float4*)(pw2+8), *(const float4*)(pw2+12));
    if (t < 64) lb1[t] = b1[t];
    else if (t < 128) lb2[t-64] = b2[t-64];
  }
  __syncthreads();

  const int lane = t & 63, wave = t >> 6;
  const int l15 = lane & 15, l4 = lane >> 4;
  const int rs = wave*16;

  // layer 1 (K=32)
  {
    bf16x8 a = *(const bf16x8*)(in_t + (rs + l15)*40 + l4*8);
    #pragma unroll
    for (int ct = 0; ct < 4; ++ct) {
      f32x4 acc = {0.f,0.f,0.f,0.f};
      bf16x8 bw = *(const bf16x8*)(w1t + (ct*16 + l15)*40 + l4*8);
      acc = MFMA_B16(a, bw, acc);
      float bias = lb1[ct*16 + l15];
      #pragma unroll
      for (int i = 0; i < 4; ++i) {
        float v = fmaxf(acc[i] + bias, 0.f);
        t1t[(rs + l4*4 + i)*88 + ct*16 + l15] = (u16)f2bs(v);
      }
    }
  }
  __syncthreads();

  // layer 2 (K=64): f32 out (optional) + bf16 restage into xe
  {
    bf16x8 a0 = *(const bf16x8*)(t1t + (rs + l15)*88 + l4*8);
    bf16x8 a1 = *(const bf16x8*)(t1t + (rs + l15)*88 + 32 + l4*8);
    #pragma unroll
    for (int ct = 0; ct < 4; ++ct) {
      f32x4 acc = {0.f,0.f,0.f,0.f};
      bf16x8 b0 = *(const bf16x8*)(w2t + (ct*16 + l15)*88 + l4*8);
      bf16x8 b1v = *(const bf16x8*)(w2t + (ct*16 + l15)*88 + 32 + l4*8);
      acc = MFMA_B16(a0, b0, acc);
      acc = MFMA_B16(a1, b1v, acc);
      float bias = lb2[ct*16 + l15];
      #pragma unroll
      for (int i = 0; i < 4; ++i) {
        float v = fmaxf(acc[i] + bias, 0.f);
        size_t gr = row0 + rs + l4*4 + i;
        int col = ct*16 + l15;
        if (out_f32) out_f32[gr*64 + col] = v;
        xe[(rs + l4*4 + i)*72 + col] = (u16)f2bs(v);
      }
    }
  }
  __syncthreads();

  // GI GEMM (plain layout) -> gst
  {
    bf16x8 xb0 = *(const bf16x8*)(xe + (rs + l15)*72 + l4*8);
    bf16x8 xb1 = *(const bf16x8*)(xe + (rs + l15)*72 + 32 + l4*8);
    #pragma unroll
    for (int g = 0; g < 3; ++g) {
      #pragma unroll
      for (int m = 0; m < 4; ++m) {
        int wr = g*64 + m*16 + l15;
        bf16x8 a0 = bfrag_f32(GW + (size_t)wr*wstride + wcoloff + l4*8);
        bf16x8 a1 = bfrag_f32(GW + (size_t)wr*wstride + wcoloff + 32 + l4*8);
        int cbase = g*64 + m*16 + 4*l4;
        float4 c1 = *(const float4*)(gbi + cbase);
        f32x4 cin; cin[0]=c1.x; cin[1]=c1.y; cin[2]=c1.z; cin[3]=c1.w;
        if (g < 2) {
          float4 c2 = *(const float4*)(gbh + cbase);
          cin[0]+=c2.x; cin[1]+=c2.y; cin[2]+=c2.z; cin[3]+=c2.w;
        }
        f32x4 acc = MFMA_B16(a0, xb0, cin);
        acc       = MFMA_B16(a1, xb1, acc);
        uint2 o; o.x = cvtpk(acc[0], acc[1]); o.y = cvtpk(acc[2], acc[3]);
        *(uint2*)(gst + (rs + l15)*200 + cbase) = o;
      }
    }
  }
  __syncthreads();

  // block-linear coalesced store of gst -> gi buffers
  if (!gi1) {
    // inf: [64][192] -> gi0 rows row0.., stride 192
    #pragma unroll
    for (int k = 0; k < 6; ++k) {
      int idx = t + k*256;          // 1536 chunks of 8 u16
      int row = idx / 24, ch = idx % 24;
      *(uint4*)(gi0 + (row0 + row)*192 + ch*8) =
          *(const uint4*)(gst + row*200 + ch*8);
    }
  } else {
    // gen: cols 0..127 -> gia (stride 128); cols 128..191 -> gib (stride 64)
    #pragma unroll
    for (int k = 0; k < 4; ++k) {
      int idx = t + k*256;          // 1024 chunks
      int row = idx / 16, ch = idx % 16;
      *(uint4*)(gi0 + (row0 + row)*128 + ch*8) =
          *(const uint4*)(gst + row*200 + ch*8);
    }
    #pragma unroll
    for (int k = 0; k < 2; ++k) {
      int idx = t + k*256;          // 512 chunks
      int row = idx / 8, ch = idx % 8;
      *(uint4*)(gi1 + (row0 + row)*64 + ch*8) =
          *(const uint4*)(gst + row*200 + 128 + ch*8);
    }
  }
}

__global__ __launch_bounds__(256) void k_pre2(
    const float* __restrict__ obs,
    const float* __restrict__ pxW1, const float* __restrict__ pxb1,
    const float* __restrict__ pxW2, const float* __restrict__ pxb2,
    float* __restrict__ xembf32,
    const float* __restrict__ iWih,
    const float* __restrict__ ibih, const float* __restrict__ ibhh,
    u16* __restrict__ gi_inf,
    const float* __restrict__ ext,
    const float* __restrict__ puW1, const float* __restrict__ pub1,
    const float* __restrict__ puW2, const float* __restrict__ pub2,
    const float* __restrict__ gWih,
    const float* __restrict__ gbih, const float* __restrict__ gbhh,
    u16* __restrict__ gia, u16* __restrict__ gib)
{
  int bid = blockIdx.x;
  if (bid < NT)
    pre_body(bid, obs, pxW1, pxb1, pxW2, pxb2, xembf32,
             iWih, 64, 0, ibih, ibhh, gi_inf, nullptr);
  else
    pre_body(bid - NT, ext, puW1, pub1, puW2, pub2, nullptr,
             gWih, 128, 64, gbih, gbhh, gia, gib);
}

// ---------------------------------------------------------------------------
// K2: posterior DBlock + sample + z_emb + GI_gen finalize (plain layout).
// ---------------------------------------------------------------------------
__global__ __launch_bounds__(256) void k_posterior_z(
    const u16* __restrict__ dseq,             // [LB][64] bf16
    const float* __restrict__ eps,            // [LB][32]
    const float* __restrict__ W1, const float* __restrict__ b1,
    const float* __restrict__ W2, const float* __restrict__ b2,
    const float* __restrict__ Wmu, const float* __restrict__ bmu,
    const float* __restrict__ Wls, const float* __restrict__ bls,
    const float* __restrict__ zW1, const float* __restrict__ zb1,
    const float* __restrict__ zW2, const float* __restrict__ zb2,
    const float* __restrict__ gWih,
    float* __restrict__ out_mu, float* __restrict__ out_ls, float* __restrict__ out_s,
    u16* __restrict__ gia, u16* __restrict__ gib)
{
  __shared__ u16 dt[64*88], w1t[64*88], w2t[64*88], tt[64*88], zw2t[64*88];
  __shared__ u16 zw1t[64*40], st[64*40];
  __shared__ u16 wmut[32*88], wlst[32*88];
  __shared__ float lb1[64], lb2[64], lbz1[64], lbz2[64], lbmu[32], lbls[32];

  const int t = threadIdx.x;
  const size_t row0 = (size_t)blockIdx.x * 64;

  {
    int r = t>>2, q = t&3;
    const u16* pd = dseq + (row0 + r)*64 + q*16;
    *(bf16x8*)(dt + r*88 + q*16)     = *(const bf16x8*)pd;
    *(bf16x8*)(dt + r*88 + q*16 + 8) = *(const bf16x8*)(pd + 8);
    const float* p1 = W1 + r*64 + q*16;
    store8(w1t + r*88 + q*16,     *(const float4*)p1,     *(const float4*)(p1+4));
    store8(w1t + r*88 + q*16 + 8, *(const float4*)(p1+8), *(const float4*)(p1+12));
    const float* p2 = W2 + r*64 + q*16;
    store8(w2t + r*88 + q*16,     *(const float4*)p2,     *(const float4*)(p2+4));
    store8(w2t + r*88 + q*16 + 8, *(const float4*)(p2+8), *(const float4*)(p2+12));
    const float* pz2 = zW2 + r*64 + q*16;
    store8(zw2t + r*88 + q*16,     *(const float4*)pz2,     *(const float4*)(pz2+4));
    store8(zw2t + r*88 + q*16 + 8, *(const float4*)(pz2+8), *(const float4*)(pz2+12));
    const float* pz1 = zW1 + r*32 + q*8;
    store8(zw1t + r*40 + q*8, *(const float4*)pz1, *(const float4*)(pz1+4));
    if (t < 128) {
      int r2 = t>>2, q2 = t&3;
      const float* pm = Wmu + r2*64 + q2*16;
      store8(wmut + r2*88 + q2*16,     *(const float4*)pm,     *(const float4*)(pm+4));
      store8(wmut + r2*88 + q2*16 + 8, *(const float4*)(pm+8), *(const float4*)(pm+12));
    } else {
      int t2 = t - 128; int r2 = t2>>2, q2 = t2&3;
      const float* pl = Wls + r2*64 + q2*16;
      store8(wlst + r2*88 + q2*16,     *(const float4*)pl,     *(const float4*)(pl+4));
      store8(wlst + r2*88 + q2*16 + 8, *(const float4*)(pl+8), *(const float4*)(pl+12));
    }
    if (t < 64) { lb1[t] = b1[t]; lbz1[t] = zb1[t]; }
    else if (t < 128) { lb2[t-64] = b2[t-64]; lbz2[t-64] = zb2[t-64]; }
    else if (t < 160) lbmu[t-128] = bmu[t-128];
    else if (t < 192) lbls[t-160] = bls[t-160];
  }
  __syncthreads();

  const int lane = t & 63, wave = t >> 6;
  const int l15 = lane & 15, l4 = lane >> 4;
  const int rs = wave*16;

  // gated hidden
  {
    bf16x8 a0 = *(const bf16x8*)(dt + (rs + l15)*88 + l4*8);
    bf16x8 a1 = *(const bf16x8*)(dt + (rs + l15)*88 + 32 + l4*8);
    #pragma unroll
    for (int ct = 0; ct < 4; ++ct) {
      f32x4 c1 = {0.f,0.f,0.f,0.f}, c2 = {0.f,0.f,0.f,0.f};
      bf16x8 w1a = *(const bf16x8*)(w1t + (ct*16 + l15)*88 + l4*8);
      bf16x8 w1b = *(const bf16x8*)(w1t + (ct*16 + l15)*88 + 32 + l4*8);
      bf16x8 w2a = *(const bf16x8*)(w2t + (ct*16 + l15)*88 + l4*8);
      bf16x8 w2b = *(const bf16x8*)(w2t + (ct*16 + l15)*88 + 32 + l4*8);
      c1 = MFMA_B16(a0, w1a, c1); c1 = MFMA_B16(a1, w1b, c1);
      c2 = MFMA_B16(a0, w2a, c2); c2 = MFMA_B16(a1, w2b, c2);
      float bb1 = lb1[ct*16 + l15], bb2 = lb2[ct*16 + l15];
      #pragma unroll
      for (int i = 0; i < 4; ++i) {
        float tv = fmaxf(c1[i] + bb1, 0.f) * fsig(c2[i] + bb2);
        tt[(rs + l4*4 + i)*88 + ct*16 + l15] = (u16)f2bs(tv);
      }
    }
  }
  __syncthreads();

  // heads + sample; park s (bf16) in st
  {
    bf16x8 a0 = *(const bf16x8*)(tt + (rs + l15)*88 + l4*8);
    bf16x8 a1 = *(const bf16x8*)(tt + (rs + l15)*88 + 32 + l4*8);
    #pragma unroll
    for (int ct = 0; ct < 2; ++ct) {
      f32x4 cmu = {0.f,0.f,0.f,0.f}, cls = {0.f,0.f,0.f,0.f};
      bf16x8 wma = *(const bf16x8*)(wmut + (ct*16 + l15)*88 + l4*8);
      bf16x8 wmb = *(const bf16x8*)(wmut + (ct*16 + l15)*88 + 32 + l4*8);
      bf16x8 wla = *(const bf16x8*)(wlst + (ct*16 + l15)*88 + l4*8);
      bf16x8 wlb = *(const bf16x8*)(wlst + (ct*16 + l15)*88 + 32 + l4*8);
      cmu = MFMA_B16(a0, wma, cmu); cmu = MFMA_B16(a1, wmb, cmu);
      cls = MFMA_B16(a0, wla, cls); cls = MFMA_B16(a1, wlb, cls);
      float bm = lbmu[ct*16 + l15], bl = lbls[ct*16 + l15];
      #pragma unroll
      for (int i = 0; i < 4; ++i) {
        size_t R = row0 + rs + l4*4 + i;
        int col = ct*16 + l15;
        float mu = cmu[i] + bm;
        float ls = cls[i] + bl;
        float e  = eps[R*32 + col];
        float s  = mu + __expf(0.5f*ls)*e;
        out_mu[R*32 + col] = mu;
        out_ls[R*32 + col] = ls;
        out_s [R*32 + col] = s;
        st[(rs + l4*4 + i)*40 + col] = (u16)f2bs(s);
      }
    }
  }
  __syncthreads();

  // z_emb layer 1 -> dt
  {
    bf16x8 a = *(const bf16x8*)(st + (rs + l15)*40 + l4*8);
    #pragma unroll
    for (int ct = 0; ct < 4; ++ct) {
      f32x4 acc = {0.f,0.f,0.f,0.f};
      bf16x8 bw = *(const bf16x8*)(zw1t + (ct*16 + l15)*40 + l4*8);
      acc = MFMA_B16(a, bw, acc);
      float bias = lbz1[ct*16 + l15];
      #pragma unroll
      for (int i = 0; i < 4; ++i) {
        float v = fmaxf(acc[i] + bias, 0.f);
        dt[(rs + l4*4 + i)*88 + ct*16 + l15] = (u16)f2bs(v);
      }
    }
  }
  __syncthreads();

  // z_emb layer 2 -> restage bf16 into w1t (dead)
  {
    bf16x8 a0 = *(const bf16x8*)(dt + (rs + l15)*88 + l4*8);
    bf16x8 a1 = *(const bf16x8*)(dt + (rs + l15)*88 + 32 + l4*8);
    #pragma unroll
    for (int ct = 0; ct < 4; ++ct) {
      f32x4 acc = {0.f,0.f,0.f,0.f};
      bf16x8 b0 = *(const bf16x8*)(zw2t + (ct*16 + l15)*88 + l4*8);
      bf16x8 b1v = *(const bf16x8*)(zw2t + (ct*16 + l15)*88 + 32 + l4*8);
      acc = MFMA_B16(a0, b0, acc);
      acc = MFMA_B16(a1, b1v, acc);
      float bias = lbz2[ct*16 + l15];
      #pragma unroll
      for (int i = 0; i < 4; ++i) {
        float v = fmaxf(acc[i] + bias, 0.f);
        w1t[(rs + l4*4 + i)*88 + ct*16 + l15] = (u16)f2bs(v);
      }
    }
  }
  __syncthreads();

  // GI_gen += gWih[:,0:64] . z_emb   (plain layout RMW)
  {
    bf16x8 xb0 = *(const bf16x8*)(w1t + (rs + l15)*88 + l4*8);
    bf16x8 xb1 = *(const bf16x8*)(w1t + (rs + l15)*88 + 32 + l4*8);
    const size_t grow = row0 + rs + l15;
    #pragma unroll
    for (int g = 0; g < 3; ++g) {
      #pragma unroll
      for (int m = 0; m < 4; ++m) {
        int wr = g*64 + m*16 + l15;
        bf16x8 a0 = bfrag_f32(gWih + (size_t)wr*128 + l4*8);
        bf16x8 a1 = bfrag_f32(gWih + (size_t)wr*128 + 32 + l4*8);
        int cbase = g*64 + m*16 + 4*l4;
        u16* p = (g < 2) ? (gia + grow*128 + cbase)
                         : (gib + grow*64 + (cbase - 128));
        uint2 part = *(const uint2*)p;
        f32x4 acc = unpk(part);
        acc = MFMA_B16(a0, xb0, acc);
        acc = MFMA_B16(a1, xb1, acc);
        uint2 o; o.x = cvtpk(acc[0], acc[1]); o.y = cvtpk(acc[2], acc[3]);
        *(uint2*)p = o;
      }
    }
  }
}

// ---------------------------------------------------------------------------
// K3/K4: GRU scan v7 — v4 4-wave exchange structure + precomputed GI.
// 64 blocks x 256 thr; block owns 16 batch rows; wave w owns gate cols
// w*16..w*16+15 of each gate (tile m = w). Lane (l15,l4): batch row l15,
// cols c0..c0+3. Per step: 3 gi uint2 loads (prefetched 2 steps ahead),
// publish h (2 cvt_pk + ds_write_b64, parity buffers), 1 raw barrier,
// 2 ds_read_b128, 6 MFMA (C-init from gi), fast gates, 1 uint2 store.
// ---------------------------------------------------------------------------
template<bool IS_GEN>
__global__ __launch_bounds__(256, 1) void k_scan(
    const u16* __restrict__ gi0,   // inf: [LB][192]; gen: gia [LB][128]
    const u16* __restrict__ gi1,   // gen: gib [LB][64]
    const float* __restrict__ Whh, // [192][64]
    const float* __restrict__ bhh, // [192]
    u16* __restrict__ dseq_out,    // inf: [LB][64] bf16
    u16* __restrict__ park,        // gen: h bf16 -> dead gia rows [LB][128]
    float* __restrict__ hn)        // gen
{
  constexpr int HT_U16 = 16*72;
  __shared__ u16 ht[2*HT_U16];

  const int t = threadIdx.x;
  const int lane = t & 63, w = t >> 6;
  const int l15 = lane & 15, l4 = lane >> 4;
  const int b0 = blockIdx.x * 16;
  const int kcol = w*16 + l15;
  const int c0   = w*16 + l4*4;

  bf16x8 whhf[3][2];
  #pragma unroll
  for (int g = 0; g < 3; ++g) {
    int wr = g*64 + kcol;
    whhf[g][0] = bfrag_f32(Whh + (size_t)wr*64 + l4*8);
    whhf[g][1] = bfrag_f32(Whh + (size_t)wr*64 + 32 + l4*8);
  }
  f32x4 bvh;
  {
    float4 b = *(const float4*)(bhh + 128 + c0);
    bvh[0]=b.x; bvh[1]=b.y; bvh[2]=b.z; bvh[3]=b.w;
  }

  auto load3 = [&](uint2 (&p)[3], int s){
    if (!IS_GEN) {
      const u16* q = gi0 + ((size_t)s*BATCH + b0 + l15)*192 + c0;
      p[0] = *(const uint2*)(q);
      p[1] = *(const uint2*)(q + 64);
      p[2] = *(const uint2*)(q + 128);
    } else {
      const u16* q = gi0 + ((size_t)s*BATCH + b0 + l15)*128 + c0;
      p[0] = *(const uint2*)(q);
      p[1] = *(const uint2*)(q + 64);
      p[2] = *(const uint2*)(gi1 + ((size_t)s*BATCH + b0 + l15)*64 + c0);
    }
  };

  float h[4] = {0.f,0.f,0.f,0.f};
  uint2 pA[3], pB[3];
  load3(pA, 0); load3(pB, 1);

  auto body = [&](uint2 (&p)[3], int s){
    // unpack this step's gi, then immediately re-issue prefetch for s+2
    f32x4 cr = unpk(p[0]);
    f32x4 cz = unpk(p[1]);
    f32x4 cn = unpk(p[2]);
    int sn = (s + 2 < L_T) ? s + 2 : L_T - 1;
    load3(p, sn);

    // publish current h (pre-update) to parity buffer
    uint2 pv; pv.x = cvtpk(h[0], h[1]); pv.y = cvtpk(h[2], h[3]);
    *(uint2*)(ht + (s&1)*HT_U16 + l15*72 + c0) = pv;
    asm volatile("s_waitcnt lgkmcnt(0)\n\ts_barrier" ::: "memory");

    const u16* hr = ht + (s&1)*HT_U16 + l15*72;
    bf16x8 ha0 = *(const bf16x8*)(hr + l4*8);
    bf16x8 ha1 = *(const bf16x8*)(hr + 32 + l4*8);

    f32x4 g0 = MFMA_B16(whhf[0][0], ha0, cr);  g0 = MFMA_B16(whhf[0][1], ha1, g0);
    f32x4 g1 = MFMA_B16(whhf[1][0], ha0, cz);  g1 = MFMA_B16(whhf[1][1], ha1, g1);
    f32x4 gn = MFMA_B16(whhf[2][0], ha0, bvh); gn = MFMA_B16(whhf[2][1], ha1, gn);

    #pragma unroll
    for (int i = 0; i < 4; ++i) {
      float r = fsig(g0[i]);
      float z = fsig(g1[i]);
      float n = ftanh(cn[i] + r*gn[i]);
      h[i] = z*(h[i] - n) + n;
    }

    uint2 dv; dv.x = cvtpk(h[0], h[1]); dv.y = cvtpk(h[2], h[3]);
    if (!IS_GEN)
      *(uint2*)(dseq_out + ((size_t)s*BATCH + b0 + l15)*64 + c0) = dv;
    else
      *(uint2*)(park + ((size_t)s*BATCH + b0 + l15)*128 + c0) = dv;
  };

  for (int s = 0; s < L_T; s += 2) {
    body(pA, s);
    body(pB, s + 1);
  }

  if (IS_GEN) {
    float4 hv; hv.x=h[0]; hv.y=h[1]; hv.z=h[2]; hv.w=h[3];
    *(float4*)(hn + ((size_t)b0 + l15)*64 + c0) = hv;
  }
}

// ---------------------------------------------------------------------------
// K5: expand parked bf16 gen-h (gia rows) to f32 hseq, shifted one step.
// hseq[t] = park[t-1] (t>=1); hseq[0] = 0.
// ---------------------------------------------------------------------------
__global__ __launch_bounds__(256) void k_expand(
    const u16* __restrict__ park,   // [LB][128] u16 rows (cols 0..63 used)
    float* __restrict__ hseq)       // [LB][64]
{
  size_t e0 = ((size_t)blockIdx.x*256 + threadIdx.x)*8;
  size_t R = e0 >> 6;
  int col = (int)(e0 & 63);
  float4 v0, v1;
  if (R < BATCH) {
    v0.x=v0.y=v0.z=v0.w=0.f; v1 = v0;
  } else {
    U8 u; u.q = *(const uint4*)(park + (R - BATCH)*128 + col);
    v0.x = __uint_as_float((unsigned)(u.u[0]) << 16);
    v0.y = __uint_as_float(u.u[0] & 0xffff0000u);
    v0.z = __uint_as_float((unsigned)(u.u[1]) << 16);
    v0.w = __uint_as_float(u.u[1] & 0xffff0000u);
    v1.x = __uint_as_float((unsigned)(u.u[2]) << 16);
    v1.y = __uint_as_float(u.u[2] & 0xffff0000u);
    v1.z = __uint_as_float((unsigned)(u.u[3]) << 16);
    v1.w = __uint_as_float(u.u[3] & 0xffff0000u);
  }
  *(float4*)(hseq + R*64 + col)     = v0;
  *(float4*)(hseq + R*64 + col + 4) = v1;
}

// ---------------------------------------------------------------------------

extern "C" void kernel_launch(void* const* d_in, const int* in_sizes, int n_in,
                              void* d_out, int out_size, void* d_ws, size_t ws_size,
                              hipStream_t stream) {
  const float* ext  = (const float*)d_in[0];
  const float* obs  = (const float*)d_in[1];
  const float* eps  = (const float*)d_in[2];
  const float* puW1 = (const float*)d_in[3];  const float* pub1 = (const float*)d_in[4];
  const float* puW2 = (const float*)d_in[5];  const float* pub2 = (const float*)d_in[6];
  const float* pxW1 = (const float*)d_in[7];  const float* pxb1 = (const float*)d_in[8];
  const float* pxW2 = (const float*)d_in[9];  const float* pxb2 = (const float*)d_in[10];
  const float* pzW1 = (const float*)d_in[11]; const float* pzb1 = (const float*)d_in[12];
  const float* pzW2 = (const float*)d_in[13]; const float* pzb2 = (const float*)d_in[14];
  const float* poW1 = (const float*)d_in[15]; const float* pob1 = (const float*)d_in[16];
  const float* poW2 = (const float*)d_in[17]; const float* pob2 = (const float*)d_in[18];
  const float* poWmu= (const float*)d_in[19]; const float* pobmu= (const float*)d_in[20];
  const float* poWls= (const float*)d_in[21]; const float* pobls= (const float*)d_in[22];
  const float* iWih = (const float*)d_in[23]; const float* iWhh = (const float*)d_in[24];
  const float* ibih = (const float*)d_in[25]; const float* ibhh = (const float*)d_in[26];
  const float* gWih = (const float*)d_in[27]; const float* gWhh = (const float*)d_in[28];
  const float* gbih = (const float*)d_in[29]; const float* gbhh = (const float*)d_in[30];

  float* out = (float*)d_out;
  const size_t OFF_MU   = 0;
  const size_t OFF_LS   = (size_t)LB*32;
  const size_t OFF_S    = (size_t)LB*64;
  const size_t OFF_HSEQ = (size_t)LB*96;
  const size_t OFF_XEMB = (size_t)LB*96 + (size_t)LB*64;
  const size_t OFF_HN   = OFF_XEMB + (size_t)LB*64;

  u16* gi_inf = (u16*)(out + OFF_MU);                   // [LB][192] bf16 (mu/ls/s park)
  u16* gia    = (u16*)d_ws;                             // [LB][128] bf16 (GI_gen g<2; later h park)
  u16* gib    = (u16*)(out + OFF_HSEQ);                 // [LB][64]  bf16 (GI_gen g=2; hseq 1st half)
  u16* dseq   = (u16*)(out + OFF_HSEQ) + (size_t)LB*64; // [LB][64]  bf16 (hseq 2nd half)

  // 1. x_emb (+GI_inf) and u_emb (+GI_gen partial)
  k_pre2<<<2*NT, 256, 0, stream>>>(obs, pxW1, pxb1, pxW2, pxb2, out + OFF_XEMB,
                                   iWih, ibih, ibhh, gi_inf,
                                   ext, puW1, pub1, puW2, pub2,
                                   gWih, gbih, gbhh, gia, gib);
  // 2. inference scan
  k_scan<false><<<64, 256, 0, stream>>>(gi_inf, nullptr, iWhh, ibhh,
                                        dseq, nullptr, nullptr);
  // 3. posterior + sample + z_emb + GI_gen finalize (overwrites gi_inf with mu/ls/s)
  k_posterior_z<<<NT, 256, 0, stream>>>(dseq, eps, poW1, pob1, poW2, pob2,
                                        poWmu, pobmu, poWls, pobls,
                                        pzW1, pzb1, pzW2, pzb2, gWih,
                                        out + OFF_MU, out + OFF_LS, out + OFF_S,
                                        gia, gib);
  // 4. generative scan (parks bf16 h into dead gia rows + writes hn)
  k_scan<true><<<64, 256, 0, stream>>>(gia, gib, gWhh, gbhh,
                                       nullptr, gia, out + OFF_HN);
  // 5. expand parked h to f32 hseq
  k_expand<<<(LB*64)/2048, 256, 0, stream>>>(gia, out + OFF_HSEQ);
}

// Round 8
// 1109.935 us; speedup vs baseline: 2.5958x; 1.3129x over previous
//
#include <hip/hip_runtime.h>

#define L_T 512
#define BATCH 1024
#define LB (L_T*BATCH)
#define NT (LB/64)

typedef short bf16x8 __attribute__((ext_vector_type(8)));
typedef float f32x4 __attribute__((ext_vector_type(4)));
typedef unsigned short u16;

#define MFMA_B16(a,b,c) __builtin_amdgcn_mfma_f32_16x16x32_bf16((a),(b),(c),0,0,0)

union U8 { unsigned u[4]; uint4 q; bf16x8 v; };

__device__ __forceinline__ short f2bs(float f){
  union{float f; unsigned u;} c; c.f=f;
  unsigned r = (c.u + 0x7FFFu + ((c.u>>16)&1u)) >> 16;
  return (short)r;
}

__device__ __forceinline__ unsigned cvtpk(float lo, float hi){
  unsigned d;
  asm("v_cvt_pk_bf16_f32 %0, %1, %2" : "=v"(d) : "v"(lo), "v"(hi));
  return d;
}

// fast activations (validated in R7: absmax unchanged)
__device__ __forceinline__ float fsig(float x){
  return __builtin_amdgcn_rcpf(1.0f + __expf(-x));
}
__device__ __forceinline__ float ftanh(float x){
  return 1.0f - 2.0f*__builtin_amdgcn_rcpf(1.0f + __expf(2.0f*x));
}

__device__ __forceinline__ void store8(u16* d, float4 a, float4 b){
  bf16x8 v;
  v[0]=f2bs(a.x); v[1]=f2bs(a.y); v[2]=f2bs(a.z); v[3]=f2bs(a.w);
  v[4]=f2bs(b.x); v[5]=f2bs(b.y); v[6]=f2bs(b.z); v[7]=f2bs(b.w);
  *(bf16x8*)d = v;
}

__device__ __forceinline__ bf16x8 bfrag_f32(const float* p){
  float4 a = *(const float4*)p;
  float4 b = *(const float4*)(p+4);
  bf16x8 v;
  v[0]=f2bs(a.x); v[1]=f2bs(a.y); v[2]=f2bs(a.z); v[3]=f2bs(a.w);
  v[4]=f2bs(b.x); v[5]=f2bs(b.y); v[6]=f2bs(b.z); v[7]=f2bs(b.w);
  return v;
}

__device__ __forceinline__ f32x4 ldbias(const float* p){
  float4 b = *(const float4*)p;
  f32x4 r; r[0]=b.x; r[1]=b.y; r[2]=b.z; r[3]=b.w;
  return r;
}

// ---------------------------------------------------------------------------
// K1: two-layer preprocess (R4 version, no GI). x-branch: f32 out + bf16 park;
// u-branch: bf16 park only.
// ---------------------------------------------------------------------------
__device__ __forceinline__ void pre_body(
    int bid,
    const float* __restrict__ src, const float* __restrict__ W1,
    const float* __restrict__ b1, const float* __restrict__ W2,
    const float* __restrict__ b2,
    u16* __restrict__ out_b16, float* __restrict__ out_f32)
{
  __shared__ u16 in_t[64*40];
  __shared__ u16 w1t[64*40];
  __shared__ u16 w2t[64*88];
  __shared__ u16 t1t[64*88];
  __shared__ float lb1[64], lb2[64];

  const int t = threadIdx.x;
  const size_t row0 = (size_t)bid * 64;

  {
    int r = t>>2, q = t&3;
    const float* ps = src + (row0 + r)*32 + q*8;
    store8(in_t + r*40 + q*8, *(const float4*)ps, *(const float4*)(ps+4));
    const float* pw = W1 + r*32 + q*8;
    store8(w1t + r*40 + q*8, *(const float4*)pw, *(const float4*)(pw+4));
    const float* pw2 = W2 + r*64 + q*16;
    store8(w2t + r*88 + q*16,     *(const float4*)pw2,     *(const float4*)(pw2+4));
    store8(w2t + r*88 + q*16 + 8, *(const float4*)(pw2+8), *(const float4*)(pw2+12));
    if (t < 64) lb1[t] = b1[t];
    else if (t < 128) lb2[t-64] = b2[t-64];
  }
  __syncthreads();

  const int lane = t & 63, wave = t >> 6;
  const int l15 = lane & 15, l4 = lane >> 4;
  const int rs = wave*16;

  {
    bf16x8 a = *(const bf16x8*)(in_t + (rs + l15)*40 + l4*8);
    #pragma unroll
    for (int ct = 0; ct < 4; ++ct) {
      f32x4 acc = {0.f,0.f,0.f,0.f};
      bf16x8 bw = *(const bf16x8*)(w1t + (ct*16 + l15)*40 + l4*8);
      acc = MFMA_B16(a, bw, acc);
      float bias = lb1[ct*16 + l15];
      #pragma unroll
      for (int i = 0; i < 4; ++i) {
        float v = fmaxf(acc[i] + bias, 0.f);
        t1t[(rs + l4*4 + i)*88 + ct*16 + l15] = (u16)f2bs(v);
      }
    }
  }
  __syncthreads();

  {
    bf16x8 a0 = *(const bf16x8*)(t1t + (rs + l15)*88 + l4*8);
    bf16x8 a1 = *(const bf16x8*)(t1t + (rs + l15)*88 + 32 + l4*8);
    #pragma unroll
    for (int ct = 0; ct < 4; ++ct) {
      f32x4 acc = {0.f,0.f,0.f,0.f};
      bf16x8 b0 = *(const bf16x8*)(w2t + (ct*16 + l15)*88 + l4*8);
      bf16x8 b1v = *(const bf16x8*)(w2t + (ct*16 + l15)*88 + 32 + l4*8);
      acc = MFMA_B16(a0, b0, acc);
      acc = MFMA_B16(a1, b1v, acc);
      float bias = lb2[ct*16 + l15];
      #pragma unroll
      for (int i = 0; i < 4; ++i) {
        float v = fmaxf(acc[i] + bias, 0.f);
        size_t gr = row0 + rs + l4*4 + i;
        int col = ct*16 + l15;
        out_b16[gr*64 + col] = (u16)f2bs(v);
        if (out_f32) out_f32[gr*64 + col] = v;
      }
    }
  }
}

__global__ __launch_bounds__(256) void k_pre2(
    const float* __restrict__ obs,
    const float* __restrict__ pxW1, const float* __restrict__ pxb1,
    const float* __restrict__ pxW2, const float* __restrict__ pxb2,
    u16* __restrict__ xemb16, float* __restrict__ xembf32,
    const float* __restrict__ ext,
    const float* __restrict__ puW1, const float* __restrict__ pub1,
    const float* __restrict__ puW2, const float* __restrict__ pub2,
    u16* __restrict__ uemb16)
{
  int bid = blockIdx.x;
  if (bid < NT) pre_body(bid, obs, pxW1, pxb1, pxW2, pxb2, xemb16, xembf32);
  else          pre_body(bid - NT, ext, puW1, pub1, puW2, pub2, uemb16, nullptr);
}

// ---------------------------------------------------------------------------
// K2: fused pipeline kernel. 64 blocks x 768 threads (12 waves):
//  waves 0-3: inf GRU (step tau), waves 4-7: gen GRU (step tau-5),
//  waves 8-11: middle stages A(t1,tau-1) B(heads+sample,tau-2)
//              C(z_emb L1,tau-3) D(z_emb L2,tau-4).
// Depth-2 parity rings in LDS; ONE barrier per tick. Roles share register
// arrays (WF/BV/PF) so allocation is max-over-roles.
// ---------------------------------------------------------------------------
__global__ __launch_bounds__(768, 1) void k_mega(
    const u16* __restrict__ xemb16,   // [LB][64] bf16
    const u16* __restrict__ uemb16,   // [LB][64] bf16
    const float* __restrict__ eps,    // [LB][32]
    const float* __restrict__ iWih, const float* __restrict__ iWhh,
    const float* __restrict__ ibih, const float* __restrict__ ibhh,
    const float* __restrict__ gWih, const float* __restrict__ gWhh,
    const float* __restrict__ gbih, const float* __restrict__ gbhh,
    const float* __restrict__ poW1, const float* __restrict__ pob1,
    const float* __restrict__ poW2, const float* __restrict__ pob2,
    const float* __restrict__ poWmu, const float* __restrict__ pobmu,
    const float* __restrict__ poWls, const float* __restrict__ pobls,
    const float* __restrict__ pzW1, const float* __restrict__ pzb1,
    const float* __restrict__ pzW2, const float* __restrict__ pzb2,
    float* __restrict__ out_mu, float* __restrict__ out_ls,
    float* __restrict__ out_s,
    float* __restrict__ hseq, float* __restrict__ hn)
{
  __shared__ u16 hinf[2][16*72];   // inf h ring (= d ring)
  __shared__ u16 t1r [2][16*72];   // DBlock gated hidden
  __shared__ u16 sr  [2][16*40];   // sampled state (bf16)
  __shared__ u16 z1r [2][16*72];   // z_emb layer1
  __shared__ u16 zer [2][16*72];   // z_emb layer2 (gen_in z-half)
  __shared__ u16 hgen[2][16*72];   // gen h ring

  const int t = threadIdx.x;
  const int lane = t & 63, wid = t >> 6;
  const int l15 = lane & 15, l4 = lane >> 4;
  const int b0 = blockIdx.x * 16;
  const int role = wid >> 2;        // 0=inf 1=gen 2=mid
  const int w = wid & 3;
  const int c0 = w*16 + l4*4;
  const int kcol = w*16 + l15;

  bf16x8 WF[18];
  f32x4 BV[6];
  U8 PF[4];
  f32x4 EPS0 = {0,0,0,0}, EPS1 = {0,0,0,0};
  float h[4] = {0.f,0.f,0.f,0.f};

  if (role == 0) {
    #pragma unroll
    for (int g = 0; g < 3; ++g) {
      int wr = g*64 + kcol;
      WF[g*2+0]   = bfrag_f32(iWih + (size_t)wr*64 + l4*8);
      WF[g*2+1]   = bfrag_f32(iWih + (size_t)wr*64 + 32 + l4*8);
      WF[6+g*2+0] = bfrag_f32(iWhh + (size_t)wr*64 + l4*8);
      WF[6+g*2+1] = bfrag_f32(iWhh + (size_t)wr*64 + 32 + l4*8);
    }
    #pragma unroll
    for (int i = 0; i < 4; ++i) {
      BV[0][i] = ibih[c0+i]      + ibhh[c0+i];
      BV[1][i] = ibih[64+c0+i]   + ibhh[64+c0+i];
      BV[2][i] = ibih[128+c0+i];
      BV[3][i] = ibhh[128+c0+i];
    }
    const u16* q0 = xemb16 + ((size_t)0*BATCH + b0 + l15)*64 + l4*8;
    const u16* q1 = xemb16 + ((size_t)1*BATCH + b0 + l15)*64 + l4*8;
    PF[0].v = *(const bf16x8*)q0; PF[1].v = *(const bf16x8*)(q0+32);
    PF[2].v = *(const bf16x8*)q1; PF[3].v = *(const bf16x8*)(q1+32);
  } else if (role == 1) {
    #pragma unroll
    for (int g = 0; g < 3; ++g) {
      int wr = g*64 + kcol;
      #pragma unroll
      for (int kc = 0; kc < 4; ++kc)
        WF[g*4+kc] = bfrag_f32(gWih + (size_t)wr*128 + kc*32 + l4*8);
      WF[12+g*2+0] = bfrag_f32(gWhh + (size_t)wr*64 + l4*8);
      WF[12+g*2+1] = bfrag_f32(gWhh + (size_t)wr*64 + 32 + l4*8);
    }
    #pragma unroll
    for (int i = 0; i < 4; ++i) {
      BV[0][i] = gbih[c0+i]      + gbhh[c0+i];
      BV[1][i] = gbih[64+c0+i]   + gbhh[64+c0+i];
      BV[2][i] = gbih[128+c0+i];
      BV[3][i] = gbhh[128+c0+i];
    }
    const u16* q0 = uemb16 + ((size_t)0*BATCH + b0 + l15)*64 + l4*8;
    const u16* q1 = uemb16 + ((size_t)1*BATCH + b0 + l15)*64 + l4*8;
    PF[0].v = *(const bf16x8*)q0; PF[1].v = *(const bf16x8*)(q0+32);
    PF[2].v = *(const bf16x8*)q1; PF[3].v = *(const bf16x8*)(q1+32);
  } else {
    WF[0] = bfrag_f32(poW1 + (size_t)kcol*64 + l4*8);
    WF[1] = bfrag_f32(poW1 + (size_t)kcol*64 + 32 + l4*8);
    WF[2] = bfrag_f32(poW2 + (size_t)kcol*64 + l4*8);
    WF[3] = bfrag_f32(poW2 + (size_t)kcol*64 + 32 + l4*8);
    if (w < 2) {
      WF[4] = bfrag_f32(poWmu + (size_t)kcol*64 + l4*8);
      WF[5] = bfrag_f32(poWmu + (size_t)kcol*64 + 32 + l4*8);
      WF[6] = bfrag_f32(poWls + (size_t)kcol*64 + l4*8);
      WF[7] = bfrag_f32(poWls + (size_t)kcol*64 + 32 + l4*8);
      BV[2] = ldbias(pobmu + c0);
      BV[3] = ldbias(pobls + c0);
      const float* pe0 = eps + ((size_t)0*BATCH + b0 + l15)*32 + c0;
      const float* pe1 = eps + ((size_t)1*BATCH + b0 + l15)*32 + c0;
      float4 e0 = *(const float4*)pe0; EPS0[0]=e0.x; EPS0[1]=e0.y; EPS0[2]=e0.z; EPS0[3]=e0.w;
      float4 e1 = *(const float4*)pe1; EPS1[0]=e1.x; EPS1[1]=e1.y; EPS1[2]=e1.z; EPS1[3]=e1.w;
    }
    WF[8]  = bfrag_f32(pzW1 + (size_t)kcol*32 + l4*8);
    WF[9]  = bfrag_f32(pzW2 + (size_t)kcol*64 + l4*8);
    WF[10] = bfrag_f32(pzW2 + (size_t)kcol*64 + 32 + l4*8);
    BV[0] = ldbias(pob1 + c0);
    BV[1] = ldbias(pob2 + c0);
    BV[4] = ldbias(pzb1 + c0);
    BV[5] = ldbias(pzb2 + c0);
  }

  const int TICKS = L_T + 5;
  for (int tau = 0; tau < TICKS; ++tau) {
    if (role == 0) {
      // ----- inf GRU, step s = tau -----
      const int s = tau;
      if (s < L_T) {
        bf16x8 xa0, xa1;
        if ((s & 1) == 0) { xa0 = PF[0].v; xa1 = PF[1].v; }
        else              { xa0 = PF[2].v; xa1 = PF[3].v; }
        {
          int sn = (s + 2 < L_T) ? s + 2 : L_T - 1;
          const u16* q = xemb16 + ((size_t)sn*BATCH + b0 + l15)*64 + l4*8;
          if ((s & 1) == 0) { PF[0].v = *(const bf16x8*)q; PF[1].v = *(const bf16x8*)(q+32); }
          else              { PF[2].v = *(const bf16x8*)q; PF[3].v = *(const bf16x8*)(q+32); }
        }
        f32x4 g0 = BV[0], g1 = BV[1], a2 = BV[2], gn = BV[3];
        g0 = MFMA_B16(WF[0], xa0, g0); g0 = MFMA_B16(WF[1], xa1, g0);
        g1 = MFMA_B16(WF[2], xa0, g1); g1 = MFMA_B16(WF[3], xa1, g1);
        a2 = MFMA_B16(WF[4], xa0, a2); a2 = MFMA_B16(WF[5], xa1, a2);
        U8 ha0, ha1;
        if (s > 0) {
          const u16* hr = hinf[(s-1)&1] + l15*72;
          ha0.v = *(const bf16x8*)(hr + l4*8);
          ha1.v = *(const bf16x8*)(hr + 32 + l4*8);
        } else {
          ha0.u[0]=ha0.u[1]=ha0.u[2]=ha0.u[3]=0;
          ha1 = ha0;
        }
        g0 = MFMA_B16(WF[6],  ha0.v, g0); g0 = MFMA_B16(WF[7],  ha1.v, g0);
        g1 = MFMA_B16(WF[8],  ha0.v, g1); g1 = MFMA_B16(WF[9],  ha1.v, g1);
        gn = MFMA_B16(WF[10], ha0.v, gn); gn = MFMA_B16(WF[11], ha1.v, gn);
        #pragma unroll
        for (int i = 0; i < 4; ++i) {
          float r = fsig(g0[i]);
          float z = fsig(g1[i]);
          float n = ftanh(a2[i] + r*gn[i]);
          h[i] = z*(h[i] - n) + n;
        }
        uint2 pv; pv.x = cvtpk(h[0], h[1]); pv.y = cvtpk(h[2], h[3]);
        *(uint2*)(hinf[s&1] + l15*72 + c0) = pv;
      }
    } else if (role == 1) {
      // ----- gen GRU, step s = tau-5 -----
      const int s = tau - 5;
      if (s >= 0 && s < L_T) {
        // pre-update state -> hseq[s]
        float4 hv; hv.x=h[0]; hv.y=h[1]; hv.z=h[2]; hv.w=h[3];
        *(float4*)(hseq + ((size_t)s*BATCH + b0 + l15)*64 + c0) = hv;

        U8 z0, z1;
        const u16* zr = zer[s&1] + l15*72;
        z0.v = *(const bf16x8*)(zr + l4*8);
        z1.v = *(const bf16x8*)(zr + 32 + l4*8);
        bf16x8 u0, u1;
        if ((s & 1) == 0) { u0 = PF[0].v; u1 = PF[1].v; }
        else              { u0 = PF[2].v; u1 = PF[3].v; }
        {
          int sn = (s + 2 < L_T) ? s + 2 : L_T - 1;
          const u16* q = uemb16 + ((size_t)sn*BATCH + b0 + l15)*64 + l4*8;
          if ((s & 1) == 0) { PF[0].v = *(const bf16x8*)q; PF[1].v = *(const bf16x8*)(q+32); }
          else              { PF[2].v = *(const bf16x8*)q; PF[3].v = *(const bf16x8*)(q+32); }
        }
        f32x4 g0 = BV[0], g1 = BV[1], a2 = BV[2], gn = BV[3];
        g0 = MFMA_B16(WF[0], z0.v, g0); g0 = MFMA_B16(WF[1], z1.v, g0);
        g0 = MFMA_B16(WF[2], u0,   g0); g0 = MFMA_B16(WF[3], u1,   g0);
        g1 = MFMA_B16(WF[4], z0.v, g1); g1 = MFMA_B16(WF[5], z1.v, g1);
        g1 = MFMA_B16(WF[6], u0,   g1); g1 = MFMA_B16(WF[7], u1,   g1);
        a2 = MFMA_B16(WF[8], z0.v, a2); a2 = MFMA_B16(WF[9], z1.v, a2);
        a2 = MFMA_B16(WF[10], u0,  a2); a2 = MFMA_B16(WF[11], u1,  a2);
        U8 ha0, ha1;
        if (s > 0) {
          const u16* hr = hgen[(s-1)&1] + l15*72;
          ha0.v = *(const bf16x8*)(hr + l4*8);
          ha1.v = *(const bf16x8*)(hr + 32 + l4*8);
        } else {
          ha0.u[0]=ha0.u[1]=ha0.u[2]=ha0.u[3]=0;
          ha1 = ha0;
        }
        g0 = MFMA_B16(WF[12], ha0.v, g0); g0 = MFMA_B16(WF[13], ha1.v, g0);
        g1 = MFMA_B16(WF[14], ha0.v, g1); g1 = MFMA_B16(WF[15], ha1.v, g1);
        gn = MFMA_B16(WF[16], ha0.v, gn); gn = MFMA_B16(WF[17], ha1.v, gn);
        #pragma unroll
        for (int i = 0; i < 4; ++i) {
          float r = fsig(g0[i]);
          float z = fsig(g1[i]);
          float n = ftanh(a2[i] + r*gn[i]);
          h[i] = z*(h[i] - n) + n;
        }
        uint2 pv; pv.x = cvtpk(h[0], h[1]); pv.y = cvtpk(h[2], h[3]);
        *(uint2*)(hgen[s&1] + l15*72 + c0) = pv;
      }
    } else {
      // ----- middle stages -----
      // Stage A: t1 = relu(W1 d + b1) * sig(W2 d + b2), s = tau-1
      {
        const int s = tau - 1;
        if (s >= 0 && s < L_T) {
          U8 d0, d1;
          const u16* dr = hinf[s&1] + l15*72;
          d0.v = *(const bf16x8*)(dr + l4*8);
          d1.v = *(const bf16x8*)(dr + 32 + l4*8);
          f32x4 c1 = BV[0], c2 = BV[1];
          c1 = MFMA_B16(WF[0], d0.v, c1); c1 = MFMA_B16(WF[1], d1.v, c1);
          c2 = MFMA_B16(WF[2], d0.v, c2); c2 = MFMA_B16(WF[3], d1.v, c2);
          float tv[4];
          #pragma unroll
          for (int i = 0; i < 4; ++i)
            tv[i] = fmaxf(c1[i], 0.f) * fsig(c2[i]);
          uint2 pv; pv.x = cvtpk(tv[0], tv[1]); pv.y = cvtpk(tv[2], tv[3]);
          *(uint2*)(t1r[s&1] + l15*72 + c0) = pv;
        }
      }
      // Stage B: mu/ls heads + sample, s = tau-2 (waves 8,9 only)
      {
        const int s = tau - 2;
        if (w < 2 && s >= 0 && s < L_T) {
          U8 b0f, b1f;
          const u16* tr = t1r[s&1] + l15*72;
          b0f.v = *(const bf16x8*)(tr + l4*8);
          b1f.v = *(const bf16x8*)(tr + 32 + l4*8);
          f32x4 cmu = BV[2], cls = BV[3];
          cmu = MFMA_B16(WF[4], b0f.v, cmu); cmu = MFMA_B16(WF[5], b1f.v, cmu);
          cls = MFMA_B16(WF[6], b0f.v, cls); cls = MFMA_B16(WF[7], b1f.v, cls);
          f32x4 ep;
          if ((s & 1) == 0) ep = EPS0; else ep = EPS1;
          {
            int sn = (s + 2 < L_T) ? s + 2 : L_T - 1;
            const float* pe = eps + ((size_t)sn*BATCH + b0 + l15)*32 + c0;
            float4 e = *(const float4*)pe;
            if ((s & 1) == 0) { EPS0[0]=e.x; EPS0[1]=e.y; EPS0[2]=e.z; EPS0[3]=e.w; }
            else              { EPS1[0]=e.x; EPS1[1]=e.y; EPS1[2]=e.z; EPS1[3]=e.w; }
          }
          float sv[4];
          float4 vmu, vls, vs;
          float* pm = &vmu.x; float* pl = &vls.x; float* ps = &vs.x;
          #pragma unroll
          for (int i = 0; i < 4; ++i) {
            float mu = cmu[i], ls = cls[i];
            sv[i] = mu + __expf(0.5f*ls)*ep[i];
            pm[i] = mu; pl[i] = ls; ps[i] = sv[i];
          }
          size_t R = (size_t)s*BATCH + b0 + l15;
          *(float4*)(out_mu + R*32 + c0) = vmu;
          *(float4*)(out_ls + R*32 + c0) = vls;
          *(float4*)(out_s  + R*32 + c0) = vs;
          uint2 pv; pv.x = cvtpk(sv[0], sv[1]); pv.y = cvtpk(sv[2], sv[3]);
          *(uint2*)(sr[s&1] + l15*40 + c0) = pv;
        }
      }
      // Stage C: z1 = relu(zW1 s + zb1), s = tau-3
      {
        const int s = tau - 3;
        if (s >= 0 && s < L_T) {
          U8 sf;
          sf.v = *(const bf16x8*)(sr[s&1] + l15*40 + l4*8);
          f32x4 a = BV[4];
          a = MFMA_B16(WF[8], sf.v, a);
          float zv[4];
          #pragma unroll
          for (int i = 0; i < 4; ++i) zv[i] = fmaxf(a[i], 0.f);
          uint2 pv; pv.x = cvtpk(zv[0], zv[1]); pv.y = cvtpk(zv[2], zv[3]);
          *(uint2*)(z1r[s&1] + l15*72 + c0) = pv;
        }
      }
      // Stage D: z_emb = relu(zW2 z1 + zb2), s = tau-4
      {
        const int s = tau - 4;
        if (s >= 0 && s < L_T) {
          U8 za, zb;
          const u16* zr = z1r[s&1] + l15*72;
          za.v = *(const bf16x8*)(zr + l4*8);
          zb.v = *(const bf16x8*)(zr + 32 + l4*8);
          f32x4 a = BV[5];
          a = MFMA_B16(WF[9], za.v, a); a = MFMA_B16(WF[10], zb.v, a);
          float zv[4];
          #pragma unroll
          for (int i = 0; i < 4; ++i) zv[i] = fmaxf(a[i], 0.f);
          uint2 pv; pv.x = cvtpk(zv[0], zv[1]); pv.y = cvtpk(zv[2], zv[3]);
          *(uint2*)(zer[s&1] + l15*72 + c0) = pv;
        }
      }
    }
    asm volatile("s_waitcnt lgkmcnt(0)\n\ts_barrier" ::: "memory");
  }

  if (role == 1) {
    float4 hv; hv.x=h[0]; hv.y=h[1]; hv.z=h[2]; hv.w=h[3];
    *(float4*)(hn + ((size_t)b0 + l15)*64 + c0) = hv;
  }
}

// ---------------------------------------------------------------------------

extern "C" void kernel_launch(void* const* d_in, const int* in_sizes, int n_in,
                              void* d_out, int out_size, void* d_ws, size_t ws_size,
                              hipStream_t stream) {
  const float* ext  = (const float*)d_in[0];
  const float* obs  = (const float*)d_in[1];
  const float* eps  = (const float*)d_in[2];
  const float* puW1 = (const float*)d_in[3];  const float* pub1 = (const float*)d_in[4];
  const float* puW2 = (const float*)d_in[5];  const float* pub2 = (const float*)d_in[6];
  const float* pxW1 = (const float*)d_in[7];  const float* pxb1 = (const float*)d_in[8];
  const float* pxW2 = (const float*)d_in[9];  const float* pxb2 = (const float*)d_in[10];
  const float* pzW1 = (const float*)d_in[11]; const float* pzb1 = (const float*)d_in[12];
  const float* pzW2 = (const float*)d_in[13]; const float* pzb2 = (const float*)d_in[14];
  const float* poW1 = (const float*)d_in[15]; const float* pob1 = (const float*)d_in[16];
  const float* poW2 = (const float*)d_in[17]; const float* pob2 = (const float*)d_in[18];
  const float* poWmu= (const float*)d_in[19]; const float* pobmu= (const float*)d_in[20];
  const float* poWls= (const float*)d_in[21]; const float* pobls= (const float*)d_in[22];
  const float* iWih = (const float*)d_in[23]; const float* iWhh = (const float*)d_in[24];
  const float* ibih = (const float*)d_in[25]; const float* ibhh = (const float*)d_in[26];
  const float* gWih = (const float*)d_in[27]; const float* gWhh = (const float*)d_in[28];
  const float* gbih = (const float*)d_in[29]; const float* gbhh = (const float*)d_in[30];

  float* out = (float*)d_out;
  const size_t OFF_MU   = 0;
  const size_t OFF_LS   = (size_t)LB*32;
  const size_t OFF_S    = (size_t)LB*64;
  const size_t OFF_HSEQ = (size_t)LB*96;
  const size_t OFF_XEMB = (size_t)LB*96 + (size_t)LB*64;
  const size_t OFF_HN   = OFF_XEMB + (size_t)LB*64;

  u16* xemb16 = (u16*)d_ws;                   // [LB][64] bf16
  u16* uemb16 = (u16*)d_ws + (size_t)LB*64;   // [LB][64] bf16

  // 1. x_emb (f32 out + bf16 park) and u_emb (bf16 park)
  k_pre2<<<2*NT, 256, 0, stream>>>(obs, pxW1, pxb1, pxW2, pxb2, xemb16, out + OFF_XEMB,
                                   ext, puW1, pub1, puW2, pub2, uemb16);
  // 2. fused pipeline: inf scan + posterior + sample + z_emb + gen scan
  k_mega<<<64, 768, 0, stream>>>(xemb16, uemb16, eps,
                                 iWih, iWhh, ibih, ibhh,
                                 gWih, gWhh, gbih, gbhh,
                                 poW1, pob1, poW2, pob2,
                                 poWmu, pobmu, poWls, pobls,
                                 pzW1, pzb1, pzW2, pzb2,
                                 out + OFF_MU, out + OFF_LS, out + OFF_S,
                                 out + OFF_HSEQ, out + OFF_HN);
}